// Round 10
// baseline (95.760 us; speedup 1.0000x reference)
//
#include <hip/hip_runtime.h>
#include <hip/hip_bf16.h>
#include <math.h>

#define S_LEN 2048
#define NHEAD 16
#define DHEAD 128

typedef __attribute__((ext_vector_type(8)))  _Float16 f16x8;
typedef __attribute__((ext_vector_type(4)))  _Float16 f16x4;
typedef __attribute__((ext_vector_type(4)))  float    f32x4;
typedef __attribute__((ext_vector_type(16))) float    f32x16;

// vdst.hi32lanes <-> vsrc.lo32lanes   (HW-verified by round-2 passing)
__device__ __forceinline__ void permswap(unsigned &a, unsigned &b) {
    asm volatile("v_permlane32_swap_b32 %0, %1" : "+v"(a), "+v"(b));
}

// async global->LDS, 16B per lane; LDS dest = wave-uniform base + lane*16
typedef __attribute__((address_space(3))) unsigned int lds_u32;
typedef __attribute__((address_space(1))) const unsigned int glb_u32;
__device__ __forceinline__ void gload16(const void* g, void* l) {
    __builtin_amdgcn_global_load_lds((glb_u32*)g, (lds_u32*)l, 16, 0, 0);
}

// ---------------------------------------------------------------------------
// Kernel 1: transpose the two SVD weight mats [H][d][e] f32 -> [H][e][d] f16
// ---------------------------------------------------------------------------
__global__ __launch_bounds__(256) void transpose_w_kernel(
    const float* __restrict__ w_qk, const float* __restrict__ w_v,
    _Float16* __restrict__ wqk_t, _Float16* __restrict__ wv_t)
{
    __shared__ float tile[32][33];
    const int mat = blockIdx.z;
    const int h   = blockIdx.y;
    const int t0  = blockIdx.x;
    const int dt  = (t0 >> 2) * 32;
    const int et  = (t0 & 3) * 32;
    const float* src = (mat ? w_v : w_qk) + (size_t)h * DHEAD * DHEAD;
    _Float16*   dst = (mat ? wv_t : wqk_t) + (size_t)h * DHEAD * DHEAD;
    const int tx = threadIdx.x & 31, ty = threadIdx.x >> 5;
#pragma unroll
    for (int k = 0; k < 4; ++k)
        tile[ty + 8 * k][tx] = src[(size_t)(dt + ty + 8 * k) * DHEAD + et + tx];
    __syncthreads();
#pragma unroll
    for (int k = 0; k < 4; ++k)
        dst[(size_t)(et + ty + 8 * k) * DHEAD + dt + tx] = (_Float16)tile[tx][ty + 8 * k];
}

// ---------------------------------------------------------------------------
// Kernel 2: per-head projection via MFMA 16x16x32 f16 (round-8-verified).
//   Qp[h][s][e] = (X_q[s] @ W_qk) * log2(e)/sqrt(128)  (f16; exp2 domain, R5)
//   Kp[h][s][e] =  X_k[s] @ W_qk                       (f16)
//   Vt[h][e][s] =  X_v[s] @ W_v (plain transposed)     (f16)
// ---------------------------------------------------------------------------
__global__ __launch_bounds__(256) void proj_kernel(
    const float* __restrict__ q_in, const float* __restrict__ k_in,
    const float* __restrict__ v_in,
    const _Float16* __restrict__ wqk_t, const _Float16* __restrict__ wv_t,
    _Float16* __restrict__ Qp, _Float16* __restrict__ Kp, _Float16* __restrict__ Vt)
{
    const int h   = blockIdx.x >> 5;
    const int rb  = blockIdx.x & 31;
    const int wv  = threadIdx.x >> 6;
    const int lane = threadIdx.x & 63;
    const int r16 = lane & 15;
    const int kg  = lane >> 4;
    const int s_base = rb * 64 + wv * 16;
    const int s_row  = s_base + r16;
    // 1/sqrt(128) * log2(e)  -- softmax runs in exp2 domain (R5-verified)
    const float INV_NORM = 0.12752211758f;

    f16x8 aq[4], ak[4], av[4];
    {
        const float* qr = q_in + ((size_t)s_row * NHEAD + h) * DHEAD;
        const float* kr = k_in + ((size_t)s_row * NHEAD + h) * DHEAD;
        const float* vr = v_in + ((size_t)s_row * NHEAD + h) * DHEAD;
#pragma unroll
        for (int kb = 0; kb < 4; ++kb) {
            const int d0 = kb * 32 + kg * 8;
            const f32x4 q0 = *(const f32x4*)(qr + d0), q1 = *(const f32x4*)(qr + d0 + 4);
            const f32x4 k0 = *(const f32x4*)(kr + d0), k1 = *(const f32x4*)(kr + d0 + 4);
            const f32x4 v0 = *(const f32x4*)(vr + d0), v1 = *(const f32x4*)(vr + d0 + 4);
#pragma unroll
            for (int i = 0; i < 4; ++i) {
                aq[kb][i] = (_Float16)q0[i];  aq[kb][i + 4] = (_Float16)q1[i];
                ak[kb][i] = (_Float16)k0[i];  ak[kb][i + 4] = (_Float16)k1[i];
                av[kb][i] = (_Float16)v0[i];  av[kb][i + 4] = (_Float16)v1[i];
            }
        }
    }

    const _Float16* wq_h = wqk_t + (size_t)h * DHEAD * DHEAD;
    const _Float16* wv_h = wv_t  + (size_t)h * DHEAD * DHEAD;

#pragma unroll 2
    for (int cb = 0; cb < 8; ++cb) {
        f32x4 accq = {0.f, 0.f, 0.f, 0.f};
        f32x4 acck = {0.f, 0.f, 0.f, 0.f};
        f32x4 accv = {0.f, 0.f, 0.f, 0.f};
        const int c = cb * 16 + r16;
#pragma unroll
        for (int kb = 0; kb < 4; ++kb) {
            const f16x8 bqk = *(const f16x8*)(wq_h + (size_t)c * DHEAD + kb * 32 + kg * 8);
            const f16x8 bv  = *(const f16x8*)(wv_h + (size_t)c * DHEAD + kb * 32 + kg * 8);
            // swapped: A = weight (rows = e), B = X (cols = s)
            accq = __builtin_amdgcn_mfma_f32_16x16x32_f16(bqk, aq[kb], accq, 0, 0, 0);
            acck = __builtin_amdgcn_mfma_f32_16x16x32_f16(bqk, ak[kb], acck, 0, 0, 0);
            accv = __builtin_amdgcn_mfma_f32_16x16x32_f16(av[kb], bv,  accv, 0, 0, 0);
        }
        // Q/K: D row = e = cb*16 + kg*4 + jj, col = s = s_base + r16
        f16x4 qv, kv4;
#pragma unroll
        for (int jj = 0; jj < 4; ++jj) {
            qv[jj]  = (_Float16)(accq[jj] * INV_NORM);
            kv4[jj] = (_Float16)acck[jj];
        }
        *(f16x4*)(Qp + ((size_t)h * S_LEN + s_base + r16) * DHEAD + cb * 16 + kg * 4) = qv;
        *(f16x4*)(Kp + ((size_t)h * S_LEN + s_base + r16) * DHEAD + cb * 16 + kg * 4) = kv4;
        // V: D row = s = s_base + kg*4 + jj, col = e = c  (plain transpose)
        f16x4 vvv;
#pragma unroll
        for (int jj = 0; jj < 4; ++jj) vvv[jj] = (_Float16)accv[jj];
        *(f16x4*)(Vt + ((size_t)h * DHEAD + c) * S_LEN + s_base + kg * 4) = vvv;
    }
}

// ---------------------------------------------------------------------------
// Kernel 3: causal flash attention — R9-verified skeleton, TWO KV tiles per
// wave per iteration (depth-2 intra-wave pipeline) + joint softmax update.
// Grid (16, H); block 512 = 8 waves: qsub = w&1, role = (w>>1)&1, tsel = w>>2.
//   q-tile t = tsel ? 31-x : x; wave owns rows [64t+32qsub, +32);
//   role r handles kv tiles {4i+2r, 4i+2r+1} per lockstep iteration i.
// K staged once/block into LDS (4 tiles/iter, double-buffered = 64 KB),
// global_load_lds with inverse-swizzled source; read XOR (q&15)<<4.
// Joint A/B softmax: one max-shfl + one sum-shfl + one rescale per 2 tiles.
// exp2 domain (Q pre-scaled by log2e). V via early global loads.
// ---------------------------------------------------------------------------
__device__ __forceinline__ void stage_k4(const _Float16* kbase, _Float16* kst,
                                         int w, int lane, int par, int inext,
                                         int jmax_lock) {
#pragma unroll
    for (int cidx = 0; cidx < 4; ++cidx) {
        const int c    = 4 * w + cidx;        // 32 chunks = 4 tiles of 8KB
        const int slot = c >> 3;              // tile slot 0..3
        const int cc   = c & 7;               // 1KB chunk within tile
        const int jn   = 4 * inext + slot;
        if (jn < jmax_lock) {
            const int A    = cc * 1024 + lane * 16;          // linear tile offset
            const int srcO = A ^ (((A >> 8) & 15) << 4);     // inverse swizzle
            const char* g  = (const char*)kbase + (size_t)jn * 8192 + srcO;
            char*       l  = (char*)kst + (size_t)(slot * 2 + par) * 8192
                                        + cc * 1024;         // wave-uniform base
            gload16(g, l);
        }
    }
}

__global__ __launch_bounds__(512, 2) void attn_kernel(
    const _Float16* __restrict__ Qp, const _Float16* __restrict__ Kp,
    const _Float16* __restrict__ Vt, float* __restrict__ out)
{
    __shared__ _Float16 Kst[8][4096];     // [slot*2+parity][32x128 f16] = 64 KB
    __shared__ _Float16 obuf[4][32][132];
    __shared__ float    mlbuf[4][2][32];

    const int h    = blockIdx.y;
    const int w    = threadIdx.x >> 6;
    const int lane = threadIdx.x & 63;
    const int q    = lane & 31;
    const int hi   = lane >> 5;

    const int qsub = w & 1;
    const int role = (w >> 1) & 1;
    const int tsel = w >> 2;
    const int t    = tsel ? (31 - blockIdx.x) : blockIdx.x;
    const int pairid = qsub + tsel * 2;
    const int q0w  = t * 64 + qsub * 32;
    const int jmax = 2 * t + 1 + qsub;
    const int q_abs = q0w + q;

    const int jmax_lock = 2 * (31 - blockIdx.x) + 2;   // block-uniform
    const int I         = (jmax_lock + 3) >> 2;        // lockstep iterations

    const _Float16* qbase = Qp + ((size_t)h * S_LEN + q0w) * DHEAD;
    const _Float16* kbase = Kp + (size_t)h * S_LEN * DHEAD;
    const _Float16* vbase = Vt + (size_t)h * DHEAD * S_LEN;

    const int lqk = q * DHEAD + hi * 8;   // lane offset in row-major [s][d]
    const int lv  = q * S_LEN + hi * 8;   // lane offset in [e][s]
    const int swq = (q & 15) << 4;        // read-side swizzle for K LDS

    // Q fragments (B-operand): lane holds Q[q][16m + hi*8 + i]
    f16x8 qf[8];
#pragma unroll
    for (int m = 0; m < 8; ++m)
        qf[m] = *(const f16x8*)(qbase + lqk + m * 16);

    // O^T accumulators: acc[eb] covers e = eb*32 + (i&3)+8*(i>>2)+4*hi, col q
    f32x16 acc[4];
#pragma unroll
    for (int e = 0; e < 4; ++e)
#pragma unroll
        for (int i = 0; i < 16; ++i) acc[e][i] = 0.f;

    float m_run = -1e30f, l_run = 0.f;

    // prologue: stage tiles {0..3} into parity 0
    stage_k4(kbase, &Kst[0][0], w, lane, 0, 0, jmax_lock);

    int p = 0;
    for (int it = 0; it < I; ++it, p ^= 1) {
        __syncthreads();   // auto vmcnt(0)+lgkmcnt(0) drain: fills visible

        const int jA = 4 * it + 2 * role;
        const int jB = jA + 1;
        const bool actA = (jA < jmax);
        const bool actB = (jB < jmax);

        // --- issue async fills for iteration it+1 (opposite parity)
        if (it + 1 < I)
            stage_k4(kbase, &Kst[0][0], w, lane, p ^ 1, it + 1, jmax_lock);

        if (actA) {
            const int kv0A = jA * 32;
            const int kv0B = jB * 32;
            const char* ktA = (const char*)&Kst[(2 * role) * 2 + p][0];
            const char* ktB = (const char*)&Kst[(2 * role + 1) * 2 + p][0];

            // --- K_A from swizzled LDS, QK_A
            f16x8 kfA[8];
#pragma unroll
            for (int m = 0; m < 8; ++m) {
                const int L = q * 256 + m * 32 + hi * 16;
                kfA[m] = *(const f16x8*)(ktA + (L ^ swq));
            }
            f32x16 s0A, s1A;
#pragma unroll
            for (int i = 0; i < 16; ++i) { s0A[i] = 0.f; s1A[i] = 0.f; }
#pragma unroll
            for (int m = 0; m < 8; m += 2) {
                s0A = __builtin_amdgcn_mfma_f32_32x32x16_f16(kfA[m],     qf[m],     s0A, 0, 0, 0);
                s1A = __builtin_amdgcn_mfma_f32_32x32x16_f16(kfA[m + 1], qf[m + 1], s1A, 0, 0, 0);
            }

            // --- K_B from swizzled LDS, QK_B (independent stream)
            f16x8 kfB[8];
#pragma unroll
            for (int m = 0; m < 8; ++m) {
                const int L = q * 256 + m * 32 + hi * 16;
                kfB[m] = *(const f16x8*)(ktB + (L ^ swq));
            }
            f32x16 s0B, s1B;
#pragma unroll
            for (int i = 0; i < 16; ++i) { s0B[i] = 0.f; s1B[i] = 0.f; }
#pragma unroll
            for (int m = 0; m < 8; m += 2) {
                s0B = __builtin_amdgcn_mfma_f32_32x32x16_f16(kfB[m],     qf[m],     s0B, 0, 0, 0);
                s1B = __builtin_amdgcn_mfma_f32_32x32x16_f16(kfB[m + 1], qf[m + 1], s1B, 0, 0, 0);
            }

            // --- V_A early (latency hides under softmax A)
            f16x8 vfA[8];
#pragma unroll
            for (int e = 0; e < 4; ++e) {
                const _Float16* vp = vbase + (size_t)e * 32 * S_LEN + lv + kv0A;
                vfA[2 * e]     = *(const f16x8*)(vp);
                vfA[2 * e + 1] = *(const f16x8*)(vp + 16);
            }

            // --- S_A with causal mask
            f32x16 svA = s0A + s1A;
            if (kv0A == q0w) {
#pragma unroll
                for (int i = 0; i < 16; ++i) {
                    const int krel = (i & 3) + 8 * (i >> 2) + 4 * hi;
                    if (kv0A + krel > q_abs) svA[i] = -1e30f;
                }
            }

            // --- V_B issued after svA (caps register peak)
            f16x8 vfB[8];
#pragma unroll
            for (int e = 0; e < 4; ++e) {
                const _Float16* vp = vbase + (size_t)e * 32 * S_LEN + lv + kv0B;
                vfB[2 * e]     = *(const f16x8*)(vp);
                vfB[2 * e + 1] = *(const f16x8*)(vp + 16);
            }

            // --- S_B with inactive-mask (assignment kills garbage) + causal
            f32x16 svB;
#pragma unroll
            for (int i = 0; i < 16; ++i)
                svB[i] = actB ? (s0B[i] + s1B[i]) : -1e30f;
            if (actB && kv0B == q0w) {
#pragma unroll
                for (int i = 0; i < 16; ++i) {
                    const int krel = (i & 3) + 8 * (i >> 2) + 4 * hi;
                    if (kv0B + krel > q_abs) svB[i] = -1e30f;
                }
            }

            // --- joint max: one tree each, ONE cross-half shuffle
            float a0 = fmaxf(fmaxf(svA[0], svA[1]),   fmaxf(svA[2], svA[3]));
            float a1 = fmaxf(fmaxf(svA[4], svA[5]),   fmaxf(svA[6], svA[7]));
            float a2 = fmaxf(fmaxf(svA[8], svA[9]),   fmaxf(svA[10], svA[11]));
            float a3 = fmaxf(fmaxf(svA[12], svA[13]), fmaxf(svA[14], svA[15]));
            float b0 = fmaxf(fmaxf(svB[0], svB[1]),   fmaxf(svB[2], svB[3]));
            float b1 = fmaxf(fmaxf(svB[4], svB[5]),   fmaxf(svB[6], svB[7]));
            float b2 = fmaxf(fmaxf(svB[8], svB[9]),   fmaxf(svB[10], svB[11]));
            float b3 = fmaxf(fmaxf(svB[12], svB[13]), fmaxf(svB[14], svB[15]));
            float tm = fmaxf(fmaxf(fmaxf(a0, a1), fmaxf(a2, a3)),
                             fmaxf(fmaxf(b0, b1), fmaxf(b2, b3)));
            tm = fmaxf(tm, __shfl_xor(tm, 32, 64));

            if (__any(tm > m_run)) {        // exact skip: corr==1 otherwise
                const float mnew = fmaxf(m_run, tm);
                const float corr = exp2f(m_run - mnew);
                l_run *= corr;
#pragma unroll
                for (int e = 0; e < 4; ++e)
#pragma unroll
                    for (int i = 0; i < 16; ++i) acc[e][i] *= corr;
                m_run = mnew;
            }

            // --- exp A, pack A, PV_A (its MFMAs overlap exp B on VALU)
#pragma unroll
            for (int i = 0; i < 16; ++i) svA[i] = exp2f(svA[i] - m_run);
            unsigned uA0 = __builtin_bit_cast(unsigned, __builtin_amdgcn_cvt_pkrtz(svA[0],  svA[1]));
            unsigned uA1 = __builtin_bit_cast(unsigned, __builtin_amdgcn_cvt_pkrtz(svA[2],  svA[3]));
            unsigned uA2 = __builtin_bit_cast(unsigned, __builtin_amdgcn_cvt_pkrtz(svA[4],  svA[5]));
            unsigned uA3 = __builtin_bit_cast(unsigned, __builtin_amdgcn_cvt_pkrtz(svA[6],  svA[7]));
            unsigned uA4 = __builtin_bit_cast(unsigned, __builtin_amdgcn_cvt_pkrtz(svA[8],  svA[9]));
            unsigned uA5 = __builtin_bit_cast(unsigned, __builtin_amdgcn_cvt_pkrtz(svA[10], svA[11]));
            unsigned uA6 = __builtin_bit_cast(unsigned, __builtin_amdgcn_cvt_pkrtz(svA[12], svA[13]));
            unsigned uA7 = __builtin_bit_cast(unsigned, __builtin_amdgcn_cvt_pkrtz(svA[14], svA[15]));
            permswap(uA0, uA2); permswap(uA1, uA3);
            permswap(uA4, uA6); permswap(uA5, uA7);
            union uf8 { unsigned w[4]; f16x8 v; };
            uf8 pA0; pA0.w[0] = uA0; pA0.w[1] = uA1; pA0.w[2] = uA2; pA0.w[3] = uA3;
            uf8 pA1; pA1.w[0] = uA4; pA1.w[1] = uA5; pA1.w[2] = uA6; pA1.w[3] = uA7;
#pragma unroll
            for (int e = 0; e < 4; ++e) {
                acc[e] = __builtin_amdgcn_mfma_f32_32x32x16_f16(vfA[2 * e],     pA0.v, acc[e], 0, 0, 0);
                acc[e] = __builtin_amdgcn_mfma_f32_32x32x16_f16(vfA[2 * e + 1], pA1.v, acc[e], 0, 0, 0);
            }

            // --- exp B, pack B, PV_B
#pragma unroll
            for (int i = 0; i < 16; ++i) svB[i] = exp2f(svB[i] - m_run);
            unsigned uB0 = __builtin_bit_cast(unsigned, __builtin_amdgcn_cvt_pkrtz(svB[0],  svB[1]));
            unsigned uB1 = __builtin_bit_cast(unsigned, __builtin_amdgcn_cvt_pkrtz(svB[2],  svB[3]));
            unsigned uB2 = __builtin_bit_cast(unsigned, __builtin_amdgcn_cvt_pkrtz(svB[4],  svB[5]));
            unsigned uB3 = __builtin_bit_cast(unsigned, __builtin_amdgcn_cvt_pkrtz(svB[6],  svB[7]));
            unsigned uB4 = __builtin_bit_cast(unsigned, __builtin_amdgcn_cvt_pkrtz(svB[8],  svB[9]));
            unsigned uB5 = __builtin_bit_cast(unsigned, __builtin_amdgcn_cvt_pkrtz(svB[10], svB[11]));
            unsigned uB6 = __builtin_bit_cast(unsigned, __builtin_amdgcn_cvt_pkrtz(svB[12], svB[13]));
            unsigned uB7 = __builtin_bit_cast(unsigned, __builtin_amdgcn_cvt_pkrtz(svB[14], svB[15]));
            permswap(uB0, uB2); permswap(uB1, uB3);
            permswap(uB4, uB6); permswap(uB5, uB7);
            uf8 pB0; pB0.w[0] = uB0; pB0.w[1] = uB1; pB0.w[2] = uB2; pB0.w[3] = uB3;
            uf8 pB1; pB1.w[0] = uB4; pB1.w[1] = uB5; pB1.w[2] = uB6; pB1.w[3] = uB7;
#pragma unroll
            for (int e = 0; e < 4; ++e) {
                acc[e] = __builtin_amdgcn_mfma_f32_32x32x16_f16(vfB[2 * e],     pB0.v, acc[e], 0, 0, 0);
                acc[e] = __builtin_amdgcn_mfma_f32_32x32x16_f16(vfB[2 * e + 1], pB1.v, acc[e], 0, 0, 0);
            }

            // --- joint row-sum: trees + ONE cross-half shuffle
            float rA = ((svA[0] + svA[1]) + (svA[2] + svA[3]))
                     + ((svA[4] + svA[5]) + (svA[6] + svA[7]))
                     + ((svA[8] + svA[9]) + (svA[10] + svA[11]))
                     + ((svA[12] + svA[13]) + (svA[14] + svA[15]));
            float rB = ((svB[0] + svB[1]) + (svB[2] + svB[3]))
                     + ((svB[4] + svB[5]) + (svB[6] + svB[7]))
                     + ((svB[8] + svB[9]) + (svB[10] + svB[11]))
                     + ((svB[12] + svB[13]) + (svB[14] + svB[15]));
            float rs = rA + rB;
            rs += __shfl_xor(rs, 32, 64);
            l_run += rs;
        }
    }

    // --- KV-split combine: role1 writes partial (m,l,O) to LDS; role0 merges
    if (role) {
        if (hi == 0) { mlbuf[pairid][0][q] = m_run; mlbuf[pairid][1][q] = l_run; }
#pragma unroll
        for (int e = 0; e < 4; ++e)
#pragma unroll
            for (int i = 0; i < 16; ++i) {
                const int erow = e * 32 + (i & 3) + 8 * (i >> 2) + 4 * hi;
                obuf[pairid][q][erow] = (_Float16)acc[e][i];
            }
    }
    __syncthreads();
    if (!role) {
        const float mb = mlbuf[pairid][0][q];
        const float lb = mlbuf[pairid][1][q];
        const float ms = fmaxf(m_run, mb);
        const float ca = exp2f(m_run - ms);
        const float cb = exp2f(mb - ms);
        const float rinv = 1.0f / (l_run * ca + lb * cb);
        float* orow = out + (size_t)q_abs * (NHEAD * DHEAD) + h * DHEAD;
#pragma unroll
        for (int e = 0; e < 4; ++e) {
#pragma unroll
            for (int g = 0; g < 4; ++g) {
                f32x4 vv;
#pragma unroll
                for (int c = 0; c < 4; ++c) {
                    const int i = g * 4 + c;
                    const int erow = e * 32 + 8 * g + 4 * hi + c;
                    vv[c] = (acc[e][i] * ca + (float)obuf[pairid][q][erow] * cb) * rinv;
                }
                *(f32x4*)(orow + e * 32 + 8 * g + 4 * hi) = vv;
            }
        }
    }
}

// ---------------------------------------------------------------------------
extern "C" void kernel_launch(void* const* d_in, const int* in_sizes, int n_in,
                              void* d_out, int out_size, void* d_ws, size_t ws_size,
                              hipStream_t stream) {
    const float* q_in = (const float*)d_in[0];
    const float* k_in = (const float*)d_in[1];
    const float* v_in = (const float*)d_in[2];
    // d_in[3] = attention_mask (strict causal triu) -- implemented analytically
    const float* w_qk = (const float*)d_in[4];
    const float* w_v  = (const float*)d_in[5];
    float* out = (float*)d_out;

    const size_t mat_elems = (size_t)NHEAD * S_LEN * DHEAD;
    const size_t w_elems   = (size_t)NHEAD * DHEAD * DHEAD;
    _Float16* Qp   = (_Float16*)d_ws;
    _Float16* Kp   = Qp + mat_elems;
    _Float16* Vt   = Kp + mat_elems;
    _Float16* Wqkt = Vt + mat_elems;
    _Float16* Wvt  = Wqkt + w_elems;

    transpose_w_kernel<<<dim3(16, NHEAD, 2), dim3(256), 0, stream>>>(w_qk, w_v, Wqkt, Wvt);
    proj_kernel<<<dim3(NHEAD * 32), dim3(256), 0, stream>>>(q_in, k_in, v_in, Wqkt, Wvt, Qp, Kp, Vt);
    attn_kernel<<<dim3(16, NHEAD), dim3(512), 0, stream>>>(Qp, Kp, Vt, out);
}